// Round 2
// baseline (220.178 us; speedup 1.0000x reference)
//
#include <hip/hip_runtime.h>
#include <hip/hip_bf16.h>
#include <stdint.h>

#define MB_ 8192
#define FD  512
#define OD  512
#define KD  8704     // F*16 + F (basis + residual)
#define KBASIS 8192

typedef __attribute__((ext_vector_type(4))) float f32x4;
typedef __attribute__((ext_vector_type(8))) short bf16x8;
typedef __attribute__((ext_vector_type(4))) unsigned int u32x4;
typedef __attribute__((ext_vector_type(2))) unsigned int u32x2;

__device__ __forceinline__ void gload_lds16(const void* g, void* l) {
  __builtin_amdgcn_global_load_lds((const __attribute__((address_space(1))) void*)g,
                                   (__attribute__((address_space(3))) void*)l,
                                   16, 0, 0);
}

__device__ __forceinline__ uint32_t bf_rtn(float f) {
  uint32_t u = __float_as_uint(f);
  return (u + 0x7fffu + ((u >> 16) & 1u)) >> 16;
}

// ---------------- phase 1: t = tanh(x) fp32, xbf = bf16(x) ----------------
__global__ __launch_bounds__(256) void k_tanh(const float* __restrict__ x,
                                              float* __restrict__ t,
                                              uint16_t* __restrict__ xbf) {
  int i = blockIdx.x * 256 + threadIdx.x;   // 0 .. 2^20-1, 4 elems each
  f32x4 v = ((const f32x4*)x)[i];
  f32x4 tv;
  tv[0] = tanhf(v[0]); tv[1] = tanhf(v[1]);
  tv[2] = tanhf(v[2]); tv[3] = tanhf(v[3]);
  ((f32x4*)t)[i] = tv;
  u32x2 p;
  p[0] = bf_rtn(v[0]) | (bf_rtn(v[1]) << 16);
  p[1] = bf_rtn(v[2]) | (bf_rtn(v[3]) << 16);
  ((u32x2*)xbf)[i] = p;
}

// ---------------- phase 2: Bt[o, k] bf16 repack -----------------------------
// Bt[o, i*16+n] = coeffs[i, o, n] ; Bt[o, 8192+i] = bw[i, o]
__global__ __launch_bounds__(256) void k_bt(const float* __restrict__ coeffs,
                                            const float* __restrict__ bw,
                                            uint16_t* __restrict__ bt,
                                            float* __restrict__ out) {
  int tid = blockIdx.x * 256 + threadIdx.x;  // 0..262143
  {
    int o = tid & 511, i = tid >> 9;
    const f32x4* src = (const f32x4*)(coeffs + (((size_t)(i * 512 + o)) << 4));
    f32x4 c0 = src[0], c1 = src[1], c2 = src[2], c3 = src[3];
    u32x4 qa, qb;
    qa[0] = bf_rtn(c0[0]) | (bf_rtn(c0[1]) << 16);
    qa[1] = bf_rtn(c0[2]) | (bf_rtn(c0[3]) << 16);
    qa[2] = bf_rtn(c1[0]) | (bf_rtn(c1[1]) << 16);
    qa[3] = bf_rtn(c1[2]) | (bf_rtn(c1[3]) << 16);
    qb[0] = bf_rtn(c2[0]) | (bf_rtn(c2[1]) << 16);
    qb[1] = bf_rtn(c2[2]) | (bf_rtn(c2[3]) << 16);
    qb[2] = bf_rtn(c3[0]) | (bf_rtn(c3[1]) << 16);
    qb[3] = bf_rtn(c3[2]) | (bf_rtn(c3[3]) << 16);
    u32x4* dst = (u32x4*)(bt + (size_t)o * KD + i * 16);
    dst[0] = qa; dst[1] = qb;
  }
  {
    int o2 = tid >> 9, i2 = tid & 511;
    bt[(size_t)o2 * KD + KBASIS + i2] = (uint16_t)bf_rtn(bw[i2 * 512 + o2]);
  }
  if (tid == 0) out[(size_t)MB_ * OD] = 0.0f;   // kl output
}

// ---------------- phase 3: fused GEMM ---------------------------------------
// C[8192,512] = A[8192,8704] @ B[8704,512] ; A basis computed in-kernel from t.
// Tile 128x128, BK=64, 512 threads (8 waves, 4x2), double-buffered LDS.
// BISECTION ROUND: NO swizzle anywhere — linear LDS layout (row*128 + k*2),
// linear gload source, linear basis ds_write, linear reads. Bank conflicts
// accepted; isolates the swizzle as the correctness variable.
__global__ __launch_bounds__(512) void k_gemm(const float* __restrict__ t,
                                              const uint16_t* __restrict__ xbf,
                                              const uint16_t* __restrict__ bt,
                                              float* __restrict__ out) {
  __shared__ __align__(128) char lds[65536];  // [buf][A 16K | B 16K] x2

  const int tid  = threadIdx.x;
  const int lane = tid & 63;
  const int wid  = tid >> 6;        // 0..7
  const int wr   = wid >> 1;        // 0..3 (row group of 32)
  const int wc   = wid & 1;         // 0..1 (col group of 64)
  const int l15  = lane & 15, l4 = lane >> 4;

  // bijective XCD swizzle: each XCD gets 8 row-tiles x 4 col-tiles
  int bx  = blockIdx.x;             // 0..255
  int idx = bx >> 3;
  int rt  = (bx & 7) * 8 + (idx >> 2);   // 0..63
  int ct  = idx & 3;                     // 0..3
  const int brow = rt << 7, bcol = ct << 7;

  // global_load_lds staging geometry (16 chunks of 1KB per 16KB panel)
  const int sr   = lane >> 3;                   // row within chunk 0..7
  const int scol = (lane & 7) << 3;             // LINEAR source col (elems)
  // basis staging role: one t-value per thread
  const int arow = tid >> 2;                    // 0..127
  const int afid = tid & 3;                     // feature 0..3 within K-step
  const float* trow = t + (size_t)(brow + arow) * FD;

  f32x4 acc[2][4];
#pragma unroll
  for (int m = 0; m < 2; ++m)
#pragma unroll
    for (int n = 0; n < 4; ++n) acc[m][n] = (f32x4)0.0f;

  auto stageB = [&](int k0, int buf) {
    char* base = lds + buf * 32768 + 16384;
#pragma unroll
    for (int j = 0; j < 2; ++j) {
      int c = wid * 2 + j;
      const uint16_t* g = bt + (size_t)(bcol + c * 8 + sr) * KD + (k0 + scol);
      gload_lds16(g, base + c * 1024);
    }
  };
  auto stageAres = [&](int k0, int buf) {      // residual columns: bf16(x)
    char* base = lds + buf * 32768;
#pragma unroll
    for (int j = 0; j < 2; ++j) {
      int c = wid * 2 + j;
      const uint16_t* g = xbf + (size_t)(brow + c * 8 + sr) * FD + (k0 - KBASIS + scol);
      gload_lds16(g, base + c * 1024);
    }
  };
  auto stageAbasis = [&](int k0, int buf) {    // Chebyshev columns from fp32 t
    float tv  = trow[(k0 >> 4) + afid];
    float tv2 = tv + tv;
    uint32_t w[8];
    w[0] = 0x3f80u | (bf_rtn(tv) << 16);       // T0=1.0, T1=t (round-nearest)
    float a0 = 1.0f, a1 = tv;
#pragma unroll
    for (int p = 1; p < 8; ++p) {
      float a2 = __builtin_fmaf(tv2, a1, -a0);   // T_{2p}
      float a3 = __builtin_fmaf(tv2, a2, -a1);   // T_{2p+1}
      w[p] = bf_rtn(a2) | (bf_rtn(a3) << 16);
      a0 = a2; a1 = a3;
    }
    char* base = lds + buf * 32768;
    int c0  = afid * 32;                          // byte col of this 64B slice
    u32x4 q0, q1;
    q0[0] = w[0]; q0[1] = w[1]; q0[2] = w[2]; q0[3] = w[3];
    q1[0] = w[4]; q1[1] = w[5]; q1[2] = w[6]; q1[3] = w[7];
    *(u32x4*)(base + arow * 128 + c0)      = q0;
    *(u32x4*)(base + arow * 128 + c0 + 16) = q1;
  };

  auto compute = [&](int buf) {
    const char* ab = lds + buf * 32768;
    const char* bb = ab + 16384;
    bf16x8 a[2][2], b[2][4];
#pragma unroll
    for (int h = 0; h < 2; ++h) {
      int koffB = (h * 32 + l4 * 8) * 2;
#pragma unroll
      for (int m = 0; m < 2; ++m) {
        int row = wr * 32 + m * 16 + l15;
        a[h][m] = *(const bf16x8*)(ab + row * 128 + koffB);
      }
#pragma unroll
      for (int n = 0; n < 4; ++n) {
        int row = wc * 64 + n * 16 + l15;
        b[h][n] = *(const bf16x8*)(bb + row * 128 + koffB);
      }
    }
#pragma unroll
    for (int h = 0; h < 2; ++h)
#pragma unroll
      for (int m = 0; m < 2; ++m)
#pragma unroll
        for (int n = 0; n < 4; ++n)
          acc[m][n] = __builtin_amdgcn_mfma_f32_16x16x32_bf16(a[h][m], b[h][n],
                                                              acc[m][n], 0, 0, 0);
  };

  // software pipeline: stage(next) issued before compute(cur); 1 barrier/step
  stageB(0, 0);
  stageAbasis(0, 0);
  for (int step = 0; step < 136; ++step) {
    int buf = step & 1;
    __syncthreads();                       // stage into buf complete (vm+lgkm)
    if (step < 135) {
      int k1 = (step + 1) << 6;
      stageB(k1, buf ^ 1);
      if (k1 < KBASIS) stageAbasis(k1, buf ^ 1);
      else             stageAres(k1, buf ^ 1);
    }
    compute(buf);
  }

  // epilogue: C/D layout col=l&15, row=(l>>4)*4+r  [m89]
#pragma unroll
  for (int m = 0; m < 2; ++m)
#pragma unroll
    for (int n = 0; n < 4; ++n)
#pragma unroll
      for (int r = 0; r < 4; ++r) {
        int grow = brow + wr * 32 + m * 16 + l4 * 4 + r;
        int gcol = bcol + wc * 64 + n * 16 + l15;
        out[(size_t)grow * OD + gcol] = acc[m][n][r];
      }
}

extern "C" void kernel_launch(void* const* d_in, const int* in_sizes, int n_in,
                              void* d_out, int out_size, void* d_ws, size_t ws_size,
                              hipStream_t stream) {
  const float* x      = (const float*)d_in[0];
  const float* coeffs = (const float*)d_in[1];
  const float* bw     = (const float*)d_in[2];
  float* out = (float*)d_out;
  char* ws = (char*)d_ws;

  float*    t   = (float*)ws;                                  // 16 MB fp32 tanh
  uint16_t* xbf = (uint16_t*)(ws + (size_t)16777216);          // 8 MB bf16 x
  uint16_t* bt  = (uint16_t*)(ws + (size_t)16777216 + 8388608);// 8.5 MB bf16 B^T

  k_tanh<<<4096, 256, 0, stream>>>(x, t, xbf);
  k_bt<<<1024, 256, 0, stream>>>(coeffs, bw, bt, out);
  k_gemm<<<256, 512, 0, stream>>>(t, xbf, bt, out);
}

// Round 4
// 177.424 us; speedup vs baseline: 1.2410x; 1.2410x over previous
//
#include <hip/hip_runtime.h>
#include <hip/hip_bf16.h>
#include <stdint.h>

#define MB_ 8192
#define FD  512
#define OD  512
#define KD  8704     // F*16 + F (basis + residual)
#define KBASIS 8192
// bt2 tiled geometry: chunk(ct, ks, o) ; ks in [0,1088), o in [0,128), 16B chunks
#define BT_KS   1088
#define BT_CHUNKS_PER_CT (BT_KS * 128)          // 139264
#define BT_BYTES_PER_CT  (BT_CHUNKS_PER_CT * 16) // 2228224

typedef __attribute__((ext_vector_type(4))) float f32x4;
typedef __attribute__((ext_vector_type(8))) short bf16x8;
typedef __attribute__((ext_vector_type(4))) unsigned int u32x4;
typedef __attribute__((ext_vector_type(2))) unsigned int u32x2;

__device__ __forceinline__ void gload_lds16(const void* g, void* l) {
  __builtin_amdgcn_global_load_lds((const __attribute__((address_space(1))) void*)g,
                                   (__attribute__((address_space(3))) void*)l,
                                   16, 0, 0);
}

__device__ __forceinline__ uint32_t bf_rtn(float f) {
  uint32_t u = __float_as_uint(f);
  return (u + 0x7fffu + ((u >> 16) & 1u)) >> 16;
}

// ---------------- phase 1: t = tanh(x) fp32, xbf = bf16(x) ----------------
__global__ __launch_bounds__(256) void k_tanh(const float* __restrict__ x,
                                              float* __restrict__ t,
                                              uint16_t* __restrict__ xbf) {
  int i = blockIdx.x * 256 + threadIdx.x;   // 0 .. 2^20-1, 4 elems each
  f32x4 v = ((const f32x4*)x)[i];
  f32x4 tv;
  tv[0] = tanhf(v[0]); tv[1] = tanhf(v[1]);
  tv[2] = tanhf(v[2]); tv[3] = tanhf(v[3]);
  ((f32x4*)t)[i] = tv;
  u32x2 p;
  p[0] = bf_rtn(v[0]) | (bf_rtn(v[1]) << 16);
  p[1] = bf_rtn(v[2]) | (bf_rtn(v[3]) << 16);
  ((u32x2*)xbf)[i] = p;
}

// ---------------- phase 2: bt2 tiled repack ---------------------------------
// chunk(ct, ks, o) holds bf16 Bt[ct*128+o][ks*8 .. +8)
// where Bt[o][i*16+n] = coeffs[i,o,n] ; Bt[o][8192+i] = bw[i,o]
__global__ __launch_bounds__(256) void k_bt(const float* __restrict__ coeffs,
                                            const float* __restrict__ bw,
                                            uint16_t* __restrict__ bt2,
                                            float* __restrict__ out) {
  int tid = blockIdx.x * 256 + threadIdx.x;  // 0..262143
  {
    int o = tid & 511, i = tid >> 9;
    const f32x4* src = (const f32x4*)(coeffs + (((size_t)(i * 512 + o)) << 4));
    f32x4 c0 = src[0], c1 = src[1], c2 = src[2], c3 = src[3];
    u32x4 qa, qb;
    qa[0] = bf_rtn(c0[0]) | (bf_rtn(c0[1]) << 16);
    qa[1] = bf_rtn(c0[2]) | (bf_rtn(c0[3]) << 16);
    qa[2] = bf_rtn(c1[0]) | (bf_rtn(c1[1]) << 16);
    qa[3] = bf_rtn(c1[2]) | (bf_rtn(c1[3]) << 16);
    qb[0] = bf_rtn(c2[0]) | (bf_rtn(c2[1]) << 16);
    qb[1] = bf_rtn(c2[2]) | (bf_rtn(c2[3]) << 16);
    qb[2] = bf_rtn(c3[0]) | (bf_rtn(c3[1]) << 16);
    qb[3] = bf_rtn(c3[2]) | (bf_rtn(c3[3]) << 16);
    size_t cidx = (size_t)(o >> 7) * BT_CHUNKS_PER_CT + (size_t)(2 * i) * 128 + (o & 127);
    u32x4* base = (u32x4*)bt2;
    base[cidx]       = qa;   // kslot 2i   (n=0..7)
    base[cidx + 128] = qb;   // kslot 2i+1 (n=8..15)
  }
  {
    int o2 = tid >> 9, i2 = tid & 511;
    size_t cidx = (size_t)(o2 >> 7) * BT_CHUNKS_PER_CT + (size_t)(1024 + (i2 >> 3)) * 128 + (o2 & 127);
    bt2[cidx * 8 + (i2 & 7)] = (uint16_t)bf_rtn(bw[i2 * 512 + o2]);
  }
  if (tid == 0) out[(size_t)MB_ * OD] = 0.0f;   // kl output
}

// ---------------- phase 3: fused GEMM ---------------------------------------
// BISECTION ROUND 4: B-side k-major ONLY.
//   B panel: k-major (kslot*2048 + row*16), staged as a pure linear copy from
//            tiled bt2, read conflict-free.
//   A panel: EXACTLY round-2 (row-major row*128 + k*2, linear staging/reads,
//            direct t read in stageAbasis). 16-way conflicts on A reads kept.
__global__ __launch_bounds__(512) void k_gemm(const float* __restrict__ t,
                                              const uint16_t* __restrict__ xbf,
                                              const uint16_t* __restrict__ bt2,
                                              float* __restrict__ out) {
  __shared__ __align__(128) char lds[65536];  // [buf][A 16K | B 16K] x2

  const int tid  = threadIdx.x;
  const int lane = tid & 63;
  const int wid  = tid >> 6;        // 0..7
  const int wr   = wid >> 1;        // 0..3 (row group of 32)
  const int wc   = wid & 1;         // 0..1 (col group of 64)
  const int l15  = lane & 15, l4 = lane >> 4;

  // bijective XCD swizzle: each XCD gets 8 row-tiles x 4 col-tiles
  int bx  = blockIdx.x;             // 0..255
  int idx = bx >> 3;
  int rt  = (bx & 7) * 8 + (idx >> 2);   // 0..63
  int ct  = idx & 3;                     // 0..3
  const int brow = rt << 7, bcol = ct << 7;

  // A-side staging geometry (round-2): 16 chunks of 1KB per 16KB panel
  const int sr   = lane >> 3;                   // row within chunk 0..7
  const int scol = (lane & 7) << 3;             // LINEAR source col (elems)
  const int tsk0 = wid * 2;
  // basis staging role: one t-value per thread
  const int arow = tid >> 2;                    // 0..127
  const int afid = tid & 3;                     // feature 0..3 within K-step
  const float* trow = t + (size_t)(brow + arow) * FD;
  const char* btbase = (const char*)bt2 + (size_t)ct * BT_BYTES_PER_CT;

  f32x4 acc[2][4];
#pragma unroll
  for (int m = 0; m < 2; ++m)
#pragma unroll
    for (int n = 0; n < 4; ++n) acc[m][n] = (f32x4)0.0f;

  auto stageB = [&](int k0, int buf) {          // linear copy from tiled bt2
    char* base = lds + buf * 32768 + 16384;
    const char* g = btbase + (size_t)k0 * 256 + (size_t)lane * 16;
#pragma unroll
    for (int j = 0; j < 2; ++j) {
      int tsk = tsk0 + j;
      gload_lds16(g + tsk * 1024, base + tsk * 1024);
    }
  };
  auto stageAres = [&](int k0, int buf) {      // round-2: residual bf16(x)
    char* base = lds + buf * 32768;
#pragma unroll
    for (int j = 0; j < 2; ++j) {
      int c = tsk0 + j;
      const uint16_t* g = xbf + (size_t)(brow + c * 8 + sr) * FD + (k0 - KBASIS + scol);
      gload_lds16(g, base + c * 1024);
    }
  };
  auto stageAbasis = [&](int k0, int buf) {    // round-2: Chebyshev from fp32 t
    float tv  = trow[(k0 >> 4) + afid];
    float tv2 = tv + tv;
    uint32_t w[8];
    w[0] = 0x3f80u | (bf_rtn(tv) << 16);       // T0=1.0, T1=t
    float a0 = 1.0f, a1 = tv;
#pragma unroll
    for (int p = 1; p < 8; ++p) {
      float a2 = __builtin_fmaf(tv2, a1, -a0);   // T_{2p}
      float a3 = __builtin_fmaf(tv2, a2, -a1);   // T_{2p+1}
      w[p] = bf_rtn(a2) | (bf_rtn(a3) << 16);
      a0 = a2; a1 = a3;
    }
    char* base = lds + buf * 32768;
    int c0  = afid * 32;                          // byte col of this 64B slice
    u32x4 q0, q1;
    q0[0] = w[0]; q0[1] = w[1]; q0[2] = w[2]; q0[3] = w[3];
    q1[0] = w[4]; q1[1] = w[5]; q1[2] = w[6]; q1[3] = w[7];
    *(u32x4*)(base + arow * 128 + c0)      = q0;
    *(u32x4*)(base + arow * 128 + c0 + 16) = q1;
  };

  auto compute = [&](int buf) {
    const char* ab = lds + buf * 32768;
    const char* bb = ab + 16384;
    bf16x8 a[2][2], b[2][4];
#pragma unroll
    for (int h = 0; h < 2; ++h) {
      int koffB = (h * 32 + l4 * 8) * 2;   // A panel: row-major (round-2)
      int ks    = 4 * h + l4;              // B panel: k-major
#pragma unroll
      for (int m = 0; m < 2; ++m) {
        int row = wr * 32 + m * 16 + l15;
        a[h][m] = *(const bf16x8*)(ab + row * 128 + koffB);
      }
#pragma unroll
      for (int n = 0; n < 4; ++n) {
        int row = wc * 64 + n * 16 + l15;
        b[h][n] = *(const bf16x8*)(bb + ks * 2048 + row * 16);
      }
    }
#pragma unroll
    for (int h = 0; h < 2; ++h)
#pragma unroll
      for (int m = 0; m < 2; ++m)
#pragma unroll
        for (int n = 0; n < 4; ++n)
          acc[m][n] = __builtin_amdgcn_mfma_f32_16x16x32_bf16(a[h][m], b[h][n],
                                                              acc[m][n], 0, 0, 0);
  };

  // software pipeline: stage(next) issued before compute(cur); 1 barrier/step
  stageB(0, 0);
  stageAbasis(0, 0);
  for (int step = 0; step < 136; ++step) {
    int buf = step & 1;
    __syncthreads();                       // stage into buf complete (vm+lgkm)
    if (step < 135) {
      int k1 = (step + 1) << 6;
      stageB(k1, buf ^ 1);
      if (k1 < KBASIS) stageAbasis(k1, buf ^ 1);
      else             stageAres(k1, buf ^ 1);
    }
    compute(buf);
  }

  // epilogue: C/D layout col=l&15, row=(l>>4)*4+r  [m89]
#pragma unroll
  for (int m = 0; m < 2; ++m)
#pragma unroll
    for (int n = 0; n < 4; ++n)
#pragma unroll
      for (int r = 0; r < 4; ++r) {
        int grow = brow + wr * 32 + m * 16 + l4 * 4 + r;
        int gcol = bcol + wc * 64 + n * 16 + l15;
        out[(size_t)grow * OD + gcol] = acc[m][n][r];
      }
}

extern "C" void kernel_launch(void* const* d_in, const int* in_sizes, int n_in,
                              void* d_out, int out_size, void* d_ws, size_t ws_size,
                              hipStream_t stream) {
  const float* x      = (const float*)d_in[0];
  const float* coeffs = (const float*)d_in[1];
  const float* bw     = (const float*)d_in[2];
  float* out = (float*)d_out;
  char* ws = (char*)d_ws;

  float*    t   = (float*)ws;                                  // 16 MB fp32 tanh
  uint16_t* xbf = (uint16_t*)(ws + (size_t)16777216);          // 8 MB bf16 x
  uint16_t* bt2 = (uint16_t*)(ws + (size_t)16777216 + 8388608);// 8.5 MB tiled B

  k_tanh<<<4096, 256, 0, stream>>>(x, t, xbf);
  k_bt<<<1024, 256, 0, stream>>>(coeffs, bw, bt2, out);
  k_gemm<<<256, 512, 0, stream>>>(t, xbf, bt2, out);
}